// Round 9
// baseline (129.905 us; speedup 1.0000x reference)
//
#include <hip/hip_runtime.h>

#define BS 256
#define NS 24   // candidate slots: 4 c1-corners, 4 c2-corners, 16 "intersections"

__device__ __forceinline__ float rcpf(float x) { return __builtin_amdgcn_rcpf(x); }

// Key-only compare-exchange: v_min_u32 + v_max_u32, literal indices only
// (round-4 lesson: runtime indices -> scratch).
#define CSWAPK(A, B) do {                                         \
    const unsigned ka_ = key[A], kb_ = key[B];                    \
    key[A] = ka_ < kb_ ? ka_ : kb_;                               \
    key[B] = ka_ < kb_ ? kb_ : ka_;                               \
} while (0)

// (x,y) compare-exchange by x, literal indices
#define CSW2(x, y, I, J) do {                                     \
    const bool sw_ = (x[J] < x[I]);                               \
    const float xi_ = x[I], xj_ = x[J], yi_ = y[I], yj_ = y[J];   \
    x[I] = sw_ ? xj_ : xi_;  x[J] = sw_ ? xi_ : xj_;              \
    y[I] = sw_ ? yj_ : yi_;  y[J] = sw_ ? yi_ : yj_;              \
} while (0)

__global__ __launch_bounds__(BS, 4)
void fpdiou_kernel(const float* __restrict__ pred, const float* __restrict__ tgt,
                   float* __restrict__ out, int n, float inv_n)
{
    // One u32 per slot per thread: (y_fix16 << 16) | x_fix16 in the W frame
    // (pred-centered, pred-rotated, x128). [slot][tid]: stride BS*4 -> bank =
    // tid%32 independent of slot: conflict-free, per-thread private, no barriers.
    __shared__ unsigned s_p[NS * BS];
    __shared__ float s_red[BS / 64];

    const int tid = threadIdx.x;
    const int i = blockIdx.x * BS + tid;
    float loss = 0.f;

    if (i < n) {
        const float* pp = pred + (size_t)i * 5;
        const float* gg = tgt  + (size_t)i * 5;
        const float p0 = pp[0], p1 = pp[1], pw = pp[2], ph = pp[3], pa = pp[4];
        const float g0 = gg[0], g1 = gg[1], gw = gg[2], gh = gg[3], ga = gg[4];

        const float s1 = __sinf(pa), co1 = __cosf(pa);
        const float s2 = __sinf(ga), co2 = __cosf(ga);

        // ---- FPDIoU distance term: needs GLOBAL-frame corners (x-order) ----
        float res;
        {
            const float DX[4] = {0.5f, -0.5f, -0.5f, 0.5f};
            const float DY[4] = {0.5f,  0.5f, -0.5f, -0.5f};
            float px_[4], py_[4], gx_[4], gy_[4];
#pragma unroll
            for (int q = 0; q < 4; q++) {
                float dx = DX[q] * pw, dy = DY[q] * ph;
                px_[q] = dx * co1 - dy * s1 + p0;
                py_[q] = dx * s1 + dy * co1 + p1;
                dx = DX[q] * gw; dy = DY[q] * gh;
                gx_[q] = dx * co2 - dy * s2 + g0;
                gy_[q] = dx * s2 + dy * co2 + g1;
            }
            CSW2(px_, py_, 0, 1); CSW2(px_, py_, 2, 3);
            CSW2(px_, py_, 0, 2); CSW2(px_, py_, 1, 3); CSW2(px_, py_, 1, 2);
            CSW2(gx_, gy_, 0, 1); CSW2(gx_, gy_, 2, 3);
            CSW2(gx_, gy_, 0, 2); CSW2(gx_, gy_, 1, 3); CSW2(gx_, gy_, 1, 2);
            const float d0 = gx_[0] - px_[0];
            float d = 2.f * d0 * d0;
#pragma unroll
            for (int q = 1; q < 4; q++) {
                const float dxq = px_[q] - gx_[q];
                const float dyq = py_[q] - gy_[q];
                d += dxq * dxq + dyq * dyq;
            }
            res = d * (1.f / 4194304.f);
        }

        // ---- W frame: pred-centered, pred-rotated, x128 scaled ----
        // Angular order is rotation-invariant up to a cyclic shift (shoelace is
        // cyclic-invariant); area scale 128^2 folds into one constant.
        const float Ws = 64.f * pw, Hs = 64.f * ph;      // box1 half-extents
        const float W2s = 64.f * gw, H2s = 64.f * gh;    // box2 half-extents
        const float twoWs = 2.f * Ws, twoHs = 2.f * Hs;
        const float mtwoWs = -twoWs, mtwoHs = -twoHs;
        const float cD = co1 * co2 + s1 * s2;            // cos(ga - pa)
        const float sD = co1 * s2 - s1 * co2;            // sin(ga - pa)
        const float gx = g0 - p0, gy = g1 - p1;
        const float u2x = (co1 * gx + s1 * gy) * 128.f;  // box2 center, W frame
        const float u2y = (co1 * gy - s1 * gx) * 128.f;

        float c2wx[4], c2wy[4];
        const float SGX[4] = {1.f, -1.f, -1.f, 1.f};
        const float SGY[4] = {1.f, 1.f, -1.f, -1.f};
#pragma unroll
        for (int q = 0; q < 4; q++) {
            const float dqx = SGX[q] * W2s, dqy = SGY[q] * H2s;
            c2wx[q] = cD * dqx - sD * dqy + u2x;
            c2wy[q] = sD * dqx + cD * dqy + u2y;
        }

        // packed-coordinate constants for box1 corners / edge-constant halves
        const int iW = (int)Ws, iH = (int)Hs;
        const unsigned loW  = (unsigned)iW & 0xFFFFu;
        const unsigned loMW = (unsigned)(-iW) & 0xFFFFu;
        const unsigned hiH  = (unsigned)iH << 16;
        const unsigned hiMH = (unsigned)(-iH) << 16;

        bool mv[NS];
        unsigned vm = 0;
        float sx = 0.f, sy = 0.f;
        const float e = 1e-6f;

        // slots 0..3: c1 corners inside box2.
        // Reference pab=(W2-x2)/(2W2) in (-e,1+e)  <=>  |x2| < W2(1+2e), frame2.
        const float W2t = W2s * (1.f + 2.f * e), H2t = H2s * (1.f + 2.f * e);
        const float q1x[4] = {Ws, -Ws, -Ws, Ws};
        const float q1y[4] = {Hs, Hs, -Hs, -Hs};
        const unsigned q1p[4] = {hiH | loW, hiH | loMW, hiMH | loMW, hiMH | loW};
#pragma unroll
        for (int q = 0; q < 4; q++) {
            const float tx = q1x[q] - u2x, ty = q1y[q] - u2y;
            const float x2 = cD * tx + sD * ty;          // frame2 coords
            const float y2 = cD * ty - sD * tx;
            const bool m = (fabsf(x2) < W2t) & (fabsf(y2) < H2t);
            s_p[q * BS + tid] = q1p[q];
            mv[q] = m;
            if (m) { vm |= 1u << q; sx += q1x[q]; sy += q1y[q]; }
        }
        // slots 4..7: c2 corners inside box1 (box1 is axis-aligned in W frame)
        const float Wt = Ws * (1.f + 2.f * e), Ht = Hs * (1.f + 2.f * e);
#pragma unroll
        for (int q = 0; q < 4; q++) {
            const bool m = (fabsf(c2wx[q]) < Wt) & (fabsf(c2wy[q]) < Ht);
            s_p[(4 + q) * BS + tid] = (((unsigned)(int)c2wy[q]) << 16)
                                    | (((unsigned)(int)c2wx[q]) & 0xFFFFu);
            mv[4 + q] = m;
            if (m) { vm |= 1u << (4 + q); sx += c2wx[q]; sy += c2wy[q]; }
        }

        // per-b edge precompute (box2 edges in W frame)
        float fx[4], fy[4], afx[4], afy[4], thh[4], thv[4];
#pragma unroll
        for (int b = 0; b < 4; b++) {
            const int bn = (b + 1) & 3;
            fx[b] = c2wx[bn] - c2wx[b]; fy[b] = c2wy[bn] - c2wy[b];
            afx[b] = fabsf(fx[b]); afy[b] = fabsf(fy[b]);
            thh[b] = afy[b] * twoWs;   // |num| for horizontal box1 edges
            thv[b] = afx[b] * twoHs;   // |num| for vertical box1 edges
        }

        // slots 8..23: reference's quirky "intersections", box1 edges axis-aligned.
        // t=den_t/num in (0,1) <=> den_t*num>0 && |den_t|<|num|;
        // u=-den_u/num in (0,1) <=> den_u*num<0 && |den_u|<|num|.
        // Horizontal edge (E=x2-x1, num=fy*E): u-mask => fy*dy13<0 && |dy13|<|fy|.
        // Vertical edge (F=y2-y1, num=-fx*F): u-mask => fx*dx13<0 && |dx13|<|fx|.
        // num==0 -> products +-0 -> strict cmps false (ref's t=-1 case).
        float iix[16], iiy[16];
        // a=0: y=+Hs, x1=+Ws, E=-2Ws; t-sign: den_t*fy<0
#pragma unroll
        for (int b = 0; b < 4; b++) {
            const float dx13 = Ws - c2wx[b], dy13 = Hs - c2wy[b];
            const float dent = fx[b] * dy13 - fy[b] * dx13;
            const bool m = (dent * fy[b] < 0.f) & (fabsf(dent) < thh[b])
                         & (fy[b] * dy13 < 0.f) & (fabsf(dy13) < afy[b]);
            const float t2 = dent * rcpf(fy[b] * mtwoWs + 1e-8f);
            const float ix = fmaf(t2, mtwoWs, Ws);
            const int s = 8 + b;
            s_p[s * BS + tid] = hiH | (((unsigned)(int)ix) & 0xFFFFu);
            iix[b] = ix; iiy[b] = Hs;
            mv[s] = m;
            if (m) { vm |= 1u << s; sx += ix; sy += Hs; }
        }
        // a=1: x=-Ws, y1=+Hs, F=-2Hs; t-sign: den_t*fx>0 (num=fx*2Hs)
#pragma unroll
        for (int b = 0; b < 4; b++) {
            const float dx13 = -Ws - c2wx[b], dy13 = Hs - c2wy[b];
            const float dent = fx[b] * dy13 - fy[b] * dx13;
            const bool m = (dent * fx[b] > 0.f) & (fabsf(dent) < thv[b])
                         & (fx[b] * dx13 < 0.f) & (fabsf(dx13) < afx[b]);
            const float t2 = dent * rcpf(fx[b] * twoHs + 1e-8f);
            const float iy = fmaf(t2, mtwoHs, Hs);
            const int s = 12 + b;
            s_p[s * BS + tid] = (((unsigned)(int)iy) << 16) | loMW;
            iix[4 + b] = -Ws; iiy[4 + b] = iy;
            mv[s] = m;
            if (m) { vm |= 1u << s; sx += -Ws; sy += iy; }
        }
        // a=2: y=-Hs, x1=-Ws, E=+2Ws; t-sign: den_t*fy>0
#pragma unroll
        for (int b = 0; b < 4; b++) {
            const float dx13 = -Ws - c2wx[b], dy13 = -Hs - c2wy[b];
            const float dent = fx[b] * dy13 - fy[b] * dx13;
            const bool m = (dent * fy[b] > 0.f) & (fabsf(dent) < thh[b])
                         & (fy[b] * dy13 < 0.f) & (fabsf(dy13) < afy[b]);
            const float t2 = dent * rcpf(fy[b] * twoWs + 1e-8f);
            const float ix = fmaf(t2, twoWs, -Ws);
            const int s = 16 + b;
            s_p[s * BS + tid] = hiMH | (((unsigned)(int)ix) & 0xFFFFu);
            iix[8 + b] = ix; iiy[8 + b] = -Hs;
            mv[s] = m;
            if (m) { vm |= 1u << s; sx += ix; sy += -Hs; }
        }
        // a=3: x=+Ws, y1=-Hs, F=+2Hs; t-sign: den_t*fx<0 (num=-fx*2Hs)
#pragma unroll
        for (int b = 0; b < 4; b++) {
            const float dx13 = Ws - c2wx[b], dy13 = -Hs - c2wy[b];
            const float dent = fx[b] * dy13 - fy[b] * dx13;
            const bool m = (dent * fx[b] < 0.f) & (fabsf(dent) < thv[b])
                         & (fx[b] * dx13 < 0.f) & (fabsf(dx13) < afx[b]);
            const float t2 = dent * rcpf(fx[b] * mtwoHs + 1e-8f);
            const float iy = fmaf(t2, twoHs, -Hs);
            const int s = 20 + b;
            s_p[s * BS + tid] = (((unsigned)(int)iy) << 16) | loW;
            iix[12 + b] = Ws; iiy[12 + b] = iy;
            mv[s] = m;
            if (m) { vm |= 1u << s; sx += Ws; sy += iy; }
        }

        // ---- keys: quantized monotone-u32(pseudo-angle) | slot-idx ----
        const int k = __popc(vm);
        const float kf = (float)(k > 0 ? k : 1);
        const float rk = rcpf(kf);
        const float mx = sx * rk, my = sy * rk;
        unsigned key[NS];
#pragma unroll
        for (int s = 0; s < NS; s++) {
            const float vx = (s < 4) ? q1x[s] : (s < 8) ? c2wx[s - 4] : iix[s - 8];
            const float vy = (s < 4) ? q1y[s] : (s < 8) ? c2wy[s - 4] : iiy[s - 8];
            const float dx = vx - mx, dy = vy - my;
            const float sa = fabsf(dx) + fabsf(dy);
            float ang = copysignf(fmaf(-dx, rcpf(sa), 1.f), dy);
            // sa==0 (vertex == mean) -> NaN key, sorts last; only reachable when
            // ALL valid vertices coincide -> cr telescopes to 0 regardless. Safe.
            ang = mv[s] ? ang : 1e9f;                    // invalid -> behind valid
            unsigned bb = __float_as_uint(ang);
            bb ^= (unsigned)((int)bb >> 31) | 0x80000000u;   // monotone map
            key[s] = (bb & 0xFFFFFFE0u) | (unsigned)s;       // idx = stable tiebreak
        }

        // ---- Batcher merge-exchange network, n=24 (127 comparators), keys only ----
        // p=16
        CSWAPK(0,16); CSWAPK(1,17); CSWAPK(2,18); CSWAPK(3,19);
        CSWAPK(4,20); CSWAPK(5,21); CSWAPK(6,22); CSWAPK(7,23);
        // p=8
        CSWAPK(0,8);  CSWAPK(1,9);  CSWAPK(2,10); CSWAPK(3,11);
        CSWAPK(4,12); CSWAPK(5,13); CSWAPK(6,14); CSWAPK(7,15);
        CSWAPK(8,16); CSWAPK(9,17); CSWAPK(10,18); CSWAPK(11,19);
        CSWAPK(12,20); CSWAPK(13,21); CSWAPK(14,22); CSWAPK(15,23);
        // p=4
        CSWAPK(0,4);  CSWAPK(1,5);  CSWAPK(2,6);  CSWAPK(3,7);
        CSWAPK(8,12); CSWAPK(9,13); CSWAPK(10,14); CSWAPK(11,15);
        CSWAPK(16,20); CSWAPK(17,21); CSWAPK(18,22); CSWAPK(19,23);
        CSWAPK(4,16); CSWAPK(5,17); CSWAPK(6,18); CSWAPK(7,19);
        CSWAPK(4,8);  CSWAPK(5,9);  CSWAPK(6,10); CSWAPK(7,11);
        CSWAPK(12,16); CSWAPK(13,17); CSWAPK(14,18); CSWAPK(15,19);
        // p=2
        CSWAPK(0,2);  CSWAPK(1,3);  CSWAPK(4,6);  CSWAPK(5,7);
        CSWAPK(8,10); CSWAPK(9,11); CSWAPK(12,14); CSWAPK(13,15);
        CSWAPK(16,18); CSWAPK(17,19); CSWAPK(20,22); CSWAPK(21,23);
        CSWAPK(2,16); CSWAPK(3,17); CSWAPK(6,20); CSWAPK(7,21);
        CSWAPK(2,8);  CSWAPK(3,9);  CSWAPK(6,12); CSWAPK(7,13);
        CSWAPK(10,16); CSWAPK(11,17); CSWAPK(14,20); CSWAPK(15,21);
        CSWAPK(2,4);  CSWAPK(3,5);  CSWAPK(6,8);  CSWAPK(7,9);
        CSWAPK(10,12); CSWAPK(11,13); CSWAPK(14,16); CSWAPK(15,17);
        CSWAPK(18,20); CSWAPK(19,21);
        // p=1
        CSWAPK(0,1);  CSWAPK(2,3);  CSWAPK(4,5);  CSWAPK(6,7);
        CSWAPK(8,9);  CSWAPK(10,11); CSWAPK(12,13); CSWAPK(14,15);
        CSWAPK(16,17); CSWAPK(18,19); CSWAPK(20,21); CSWAPK(22,23);
        CSWAPK(1,16); CSWAPK(3,18); CSWAPK(5,20); CSWAPK(7,22);
        CSWAPK(1,8);  CSWAPK(3,10); CSWAPK(5,12); CSWAPK(7,14);
        CSWAPK(9,16); CSWAPK(11,18); CSWAPK(13,20); CSWAPK(15,22);
        CSWAPK(1,4);  CSWAPK(3,6);  CSWAPK(5,8);  CSWAPK(7,10);
        CSWAPK(9,12); CSWAPK(11,14); CSWAPK(13,16); CSWAPK(15,18);
        CSWAPK(17,20); CSWAPK(19,22);
        CSWAPK(1,2);  CSWAPK(3,4);  CSWAPK(5,6);  CSWAPK(7,8);
        CSWAPK(9,10); CSWAPK(11,12); CSWAPK(13,14); CSWAPK(15,16);
        CSWAPK(17,18); CSWAPK(19,20); CSWAPK(21,22);

        // ---- shoelace with pad-to-v0: positions j>=k get vertex 0, so the
        // plain 24-term wrap sum equals the k-polygon shoelace (extra terms are
        // cross(v0,v0)=0, and term k-1 -> pad(v0) IS the wrap term). ----
        unsigned wv[NS];
#pragma unroll
        for (int j = 0; j < NS; j++)
            wv[j] = s_p[(key[j] & 31u) * BS + tid];
        const unsigned w0 = wv[0];
#pragma unroll
        for (int j = 1; j < NS; j++)
            wv[j] = (j < k) ? wv[j] : w0;
        float X[NS], Y[NS];
#pragma unroll
        for (int j = 0; j < NS; j++) {
            X[j] = (float)((int)(wv[j] << 16) >> 16);   // sext low 16
            Y[j] = (float)((int)wv[j] >> 16);
        }
        float cr0 = 0.f, cr1 = 0.f, cr2 = 0.f;
#pragma unroll
        for (int j = 0; j < NS; j++) {
            const int jn = (j + 1 < NS) ? j + 1 : 0;
            const float t = X[j] * Y[jn] - Y[j] * X[jn];
            if ((j % 3) == 0) cr0 += t; else if ((j % 3) == 1) cr1 += t; else cr2 += t;
        }
        const float cr = (cr0 + cr1) + cr2;
        const float area = fabsf(cr) * (0.5f / 16384.f);   // fold 1/128^2

        // ---- IoU + loss ----
        const float a1 = pw * ph, a2 = gw * gh;
        float iou = area / (a1 + a2 - area);
        iou = fmaxf(iou, 1e-6f);
        loss = 1.f - iou + res;
    }

    // ---- block reduction: wave shuffle -> LDS -> one atomic per block ----
#pragma unroll
    for (int off = 32; off > 0; off >>= 1)
        loss += __shfl_down(loss, off, 64);
    if ((tid & 63) == 0) s_red[tid >> 6] = loss;
    __syncthreads();
    if (tid == 0) {
        float t = 0.f;
#pragma unroll
        for (int w = 0; w < BS / 64; w++) t += s_red[w];
        atomicAdd(out, t * inv_n);
    }
}

extern "C" void kernel_launch(void* const* d_in, const int* in_sizes, int n_in,
                              void* d_out, int out_size, void* d_ws, size_t ws_size,
                              hipStream_t stream)
{
    const float* pred = (const float*)d_in[0];
    const float* tgt  = (const float*)d_in[1];
    float* out = (float*)d_out;
    const int n = in_sizes[0] / 5;
    const int nblk = (n + BS - 1) / BS;

    hipMemsetAsync(out, 0, sizeof(float), stream);   // async on stream: capturable
    fpdiou_kernel<<<nblk, BS, 0, stream>>>(pred, tgt, out, n, 1.f / (float)n);
}

// Round 10
// 129.338 us; speedup vs baseline: 1.0044x; 1.0044x over previous
//
#include <hip/hip_runtime.h>

#define BS 256
#define NS 24   // candidate slots: 4 c1-corners, 4 c2-corners, 16 "intersections"

__device__ __forceinline__ float rcpf(float x) { return __builtin_amdgcn_rcpf(x); }

// Key-only compare-exchange: v_min_u32 + v_max_u32, literal indices only
// (round-4 lesson: runtime indices -> scratch).
#define CSWAPK(A, B) do {                                         \
    const unsigned ka_ = key[A], kb_ = key[B];                    \
    key[A] = ka_ < kb_ ? ka_ : kb_;                               \
    key[B] = ka_ < kb_ ? kb_ : ka_;                               \
} while (0)

// (x,y) compare-exchange by x, literal indices
#define CSW2(x, y, I, J) do {                                     \
    const bool sw_ = (x[J] < x[I]);                               \
    const float xi_ = x[I], xj_ = x[J], yi_ = y[I], yj_ = y[J];   \
    x[I] = sw_ ? xj_ : xi_;  x[J] = sw_ ? xi_ : xj_;              \
    y[I] = sw_ ? yj_ : yi_;  y[J] = sw_ ? yi_ : yj_;              \
} while (0)

__global__ __launch_bounds__(BS, 4)
void fpdiou_kernel(const float* __restrict__ pred, const float* __restrict__ tgt,
                   float* __restrict__ out, int n, float inv_n)
{
    // One u32 per slot per thread: (y_fix16 << 16) | x_fix16, coords relative to
    // pred center, scale 128. [slot][tid] layout, stride BS*4 -> bank = tid%32
    // independent of slot: conflict-free, per-thread private, no barriers.
    __shared__ unsigned s_p[NS * BS];
    __shared__ float s_red[BS / 64];

    const int tid = threadIdx.x;
    const int i = blockIdx.x * BS + tid;
    float loss = 0.f;

    if (i < n) {
        const float* pp = pred + (size_t)i * 5;
        const float* gg = tgt  + (size_t)i * 5;
        const float p0 = pp[0], p1 = pp[1], pw = pp[2], ph = pp[3], pa = pp[4];
        const float g0 = gg[0], g1 = gg[1], gw = gg[2], gh = gg[3], ga = gg[4];

        const float s1 = __sinf(pa), co1 = __cosf(pa);
        const float s2 = __sinf(ga), co2 = __cosf(ga);

        const float DX[4] = {0.5f, -0.5f, -0.5f, 0.5f};
        const float DY[4] = {0.5f,  0.5f, -0.5f, -0.5f};
        float c1x[4], c1y[4], c2x[4], c2y[4];
#pragma unroll
        for (int q = 0; q < 4; q++) {
            float dx = DX[q] * pw, dy = DY[q] * ph;
            c1x[q] = dx * co1 - dy * s1 + p0;
            c1y[q] = dx * s1 + dy * co1 + p1;
            dx = DX[q] * gw; dy = DY[q] * gh;
            c2x[q] = dx * co2 - dy * s2 + g0;
            c2y[q] = dx * s2 + dy * co2 + g1;
        }

        const float SCL = 128.f;

        // ---- FPDIoU distance term: 5-comparator sort-by-x networks ----
        float res;
        {
            float px_[4] = {c1x[0], c1x[1], c1x[2], c1x[3]};
            float py_[4] = {c1y[0], c1y[1], c1y[2], c1y[3]};
            float gx_[4] = {c2x[0], c2x[1], c2x[2], c2x[3]};
            float gy_[4] = {c2y[0], c2y[1], c2y[2], c2y[3]};
            CSW2(px_, py_, 0, 1); CSW2(px_, py_, 2, 3);
            CSW2(px_, py_, 0, 2); CSW2(px_, py_, 1, 3); CSW2(px_, py_, 1, 2);
            CSW2(gx_, gy_, 0, 1); CSW2(gx_, gy_, 2, 3);
            CSW2(gx_, gy_, 0, 2); CSW2(gx_, gy_, 1, 3); CSW2(gx_, gy_, 1, 2);
            const float d0 = gx_[0] - px_[0];
            float d = 2.f * d0 * d0;
#pragma unroll
            for (int q = 1; q < 4; q++) {
                const float dxq = px_[q] - gx_[q];
                const float dyq = py_[q] - gy_[q];
                d += dxq * dxq + dyq * dyq;
            }
            res = d * (1.f / 4194304.f);
        }

        // ---- fill 24 slots; pack coords -> LDS; validity bitmask ----
        unsigned vm = 0;
        float sx = 0.f, sy = 0.f;
        const float e = 1e-6f;

        // slots 0..3: c1 corners inside box2 (division-free threshold form)
        {
            const float ax = c2x[0], ay = c2y[0];
            const float abx = c2x[1] - ax, aby = c2y[1] - ay;
            const float adx = c2x[3] - ax, ady = c2y[3] - ay;
            const float dab = abx * abx + aby * aby;
            const float dad = adx * adx + ady * ady;
            const float lo_ab = -e * dab, hi_ab = (1.f + e) * dab;
            const float lo_ad = -e * dad, hi_ad = (1.f + e) * dad;
#pragma unroll
            for (int q = 0; q < 4; q++) {
                const float amx = c1x[q] - ax, amy = c1y[q] - ay;
                const float dot_ab = abx * amx + aby * amy;
                const float dot_ad = adx * amx + ady * amy;
                const bool m = (dot_ab > lo_ab) & (dot_ab < hi_ab)
                             & (dot_ad > lo_ad) & (dot_ad < hi_ad);
                const int xi = (int)rintf((c1x[q] - p0) * SCL);
                const int yi = (int)rintf((c1y[q] - p1) * SCL);
                s_p[q * BS + tid] = ((unsigned)yi << 16) | ((unsigned)xi & 0xFFFFu);
                if (m) { vm |= 1u << q; sx += c1x[q]; sy += c1y[q]; }
            }
        }
        // slots 4..7: c2 corners inside box1
        {
            const float ax = c1x[0], ay = c1y[0];
            const float abx = c1x[1] - ax, aby = c1y[1] - ay;
            const float adx = c1x[3] - ax, ady = c1y[3] - ay;
            const float dab = abx * abx + aby * aby;
            const float dad = adx * adx + ady * ady;
            const float lo_ab = -e * dab, hi_ab = (1.f + e) * dab;
            const float lo_ad = -e * dad, hi_ad = (1.f + e) * dad;
#pragma unroll
            for (int q = 0; q < 4; q++) {
                const float amx = c2x[q] - ax, amy = c2y[q] - ay;
                const float dot_ab = abx * amx + aby * amy;
                const float dot_ad = adx * amx + ady * amy;
                const bool m = (dot_ab > lo_ab) & (dot_ab < hi_ab)
                             & (dot_ad > lo_ad) & (dot_ad < hi_ad);
                const int xi = (int)rintf((c2x[q] - p0) * SCL);
                const int yi = (int)rintf((c2y[q] - p1) * SCL);
                s_p[(4 + q) * BS + tid] = ((unsigned)yi << 16) | ((unsigned)xi & 0xFFFFu);
                if (m) { vm |= 1u << (4 + q); sx += c2x[q]; sy += c2y[q]; }
            }
        }
        // slots 8..23: reference's quirky "intersections"; coords kept in VGPRs
        // for the key phase (static indexing). Wide independent math on the 16
        // corner-difference pairs — this ILP width is what r9's W-frame destroyed.
        float iix[16], iiy[16];
#pragma unroll
        for (int a = 0; a < 4; a++) {
            const float x1 = c1x[a], y1 = c1y[a];
            const float ex = c1x[(a + 1) & 3] - x1, ey = c1y[(a + 1) & 3] - y1;
#pragma unroll
            for (int b = 0; b < 4; b++) {
                const float x3 = c2x[b], y3 = c2y[b];
                const float fx = c2x[(b + 1) & 3] - x3, fy = c2y[(b + 1) & 3] - y3;
                const float num = fy * ex - fx * ey;
                const float dx13 = x1 - x3, dy13 = y1 - y3;
                const float den_t = fx * dy13 - fy * dx13;
                const float den_u = ex * dy13 - ey * dx13;
                // t=den_t/num in (0,1) <=> den_t*num>0 && |den_t|<|num|;
                // u=-den_u/num in (0,1) <=> den_u*num<0 && |den_u|<|num|;
                // num==0 -> products +-0 -> strict cmps false (ref's t=-1 case).
                const bool m = (den_t * num > 0.f) & (fabsf(den_t) < fabsf(num))
                             & (den_u * num < 0.f) & (fabsf(den_u) < fabsf(num));
                const float t2 = den_t * rcpf(num + 1e-8f);   // reference quirk
                const float ix = fmaf(t2, ex, x1), iy = fmaf(t2, ey, y1);
                const int s = 8 + a * 4 + b;
                iix[a * 4 + b] = ix; iiy[a * 4 + b] = iy;
                const int xi = (int)rintf((ix - p0) * SCL);
                const int yi = (int)rintf((iy - p1) * SCL);
                s_p[s * BS + tid] = ((unsigned)yi << 16) | ((unsigned)xi & 0xFFFFu);
                if (m) { vm |= 1u << s; sx += ix; sy += iy; }
            }
        }

        // ---- keys from REGISTERS: quantized monotone-u32(pseudo-angle) | idx ----
        const int k = __popc(vm);                        // no serial k++ chain
        const float kf = (float)(k > 0 ? k : 1);
        const float mx = sx / kf, my = sy / kf;
        unsigned key[NS];
#pragma unroll
        for (int s = 0; s < NS; s++) {
            const float vx = (s < 4) ? c1x[s] : (s < 8) ? c2x[s - 4] : iix[s - 8];
            const float vy = (s < 4) ? c1y[s] : (s < 8) ? c2y[s - 4] : iiy[s - 8];
            const float dx = vx - mx, dy = vy - my;
            const float sa = fabsf(dx) + fabsf(dy);
            float ang = copysignf(1.f - dx * rcpf(sa), dy);  // order == atan2 order
            // sa==0 (vertex == mean) -> NaN key sorts last; only reachable when
            // ALL valid vertices coincide -> cr telescopes to 0. Safe (r9-verified).
            ang = ((vm >> s) & 1u) ? ang : 1e9f;             // invalid -> back
            unsigned bb = __float_as_uint(ang);
            bb ^= (unsigned)((int)bb >> 31) | 0x80000000u;   // monotone map
            key[s] = (bb & 0xFFFFFFE0u) | (unsigned)s;       // idx = stable tiebreak
        }

        // ---- Batcher merge-exchange network, n=24 (127 comparators), keys only ----
        // p=16
        CSWAPK(0,16); CSWAPK(1,17); CSWAPK(2,18); CSWAPK(3,19);
        CSWAPK(4,20); CSWAPK(5,21); CSWAPK(6,22); CSWAPK(7,23);
        // p=8
        CSWAPK(0,8);  CSWAPK(1,9);  CSWAPK(2,10); CSWAPK(3,11);
        CSWAPK(4,12); CSWAPK(5,13); CSWAPK(6,14); CSWAPK(7,15);
        CSWAPK(8,16); CSWAPK(9,17); CSWAPK(10,18); CSWAPK(11,19);
        CSWAPK(12,20); CSWAPK(13,21); CSWAPK(14,22); CSWAPK(15,23);
        // p=4
        CSWAPK(0,4);  CSWAPK(1,5);  CSWAPK(2,6);  CSWAPK(3,7);
        CSWAPK(8,12); CSWAPK(9,13); CSWAPK(10,14); CSWAPK(11,15);
        CSWAPK(16,20); CSWAPK(17,21); CSWAPK(18,22); CSWAPK(19,23);
        CSWAPK(4,16); CSWAPK(5,17); CSWAPK(6,18); CSWAPK(7,19);
        CSWAPK(4,8);  CSWAPK(5,9);  CSWAPK(6,10); CSWAPK(7,11);
        CSWAPK(12,16); CSWAPK(13,17); CSWAPK(14,18); CSWAPK(15,19);
        // p=2
        CSWAPK(0,2);  CSWAPK(1,3);  CSWAPK(4,6);  CSWAPK(5,7);
        CSWAPK(8,10); CSWAPK(9,11); CSWAPK(12,14); CSWAPK(13,15);
        CSWAPK(16,18); CSWAPK(17,19); CSWAPK(20,22); CSWAPK(21,23);
        CSWAPK(2,16); CSWAPK(3,17); CSWAPK(6,20); CSWAPK(7,21);
        CSWAPK(2,8);  CSWAPK(3,9);  CSWAPK(6,12); CSWAPK(7,13);
        CSWAPK(10,16); CSWAPK(11,17); CSWAPK(14,20); CSWAPK(15,21);
        CSWAPK(2,4);  CSWAPK(3,5);  CSWAPK(6,8);  CSWAPK(7,9);
        CSWAPK(10,12); CSWAPK(11,13); CSWAPK(14,16); CSWAPK(15,17);
        CSWAPK(18,20); CSWAPK(19,21);
        // p=1
        CSWAPK(0,1);  CSWAPK(2,3);  CSWAPK(4,5);  CSWAPK(6,7);
        CSWAPK(8,9);  CSWAPK(10,11); CSWAPK(12,13); CSWAPK(14,15);
        CSWAPK(16,17); CSWAPK(18,19); CSWAPK(20,21); CSWAPK(22,23);
        CSWAPK(1,16); CSWAPK(3,18); CSWAPK(5,20); CSWAPK(7,22);
        CSWAPK(1,8);  CSWAPK(3,10); CSWAPK(5,12); CSWAPK(7,14);
        CSWAPK(9,16); CSWAPK(11,18); CSWAPK(13,20); CSWAPK(15,22);
        CSWAPK(1,4);  CSWAPK(3,6);  CSWAPK(5,8);  CSWAPK(7,10);
        CSWAPK(9,12); CSWAPK(11,14); CSWAPK(13,16); CSWAPK(15,18);
        CSWAPK(17,20); CSWAPK(19,22);
        CSWAPK(1,2);  CSWAPK(3,4);  CSWAPK(5,6);  CSWAPK(7,8);
        CSWAPK(9,10); CSWAPK(11,12); CSWAPK(13,14); CSWAPK(15,16);
        CSWAPK(17,18); CSWAPK(19,20); CSWAPK(21,22);

        // ---- shoelace with pad-to-v0: positions j>=k get vertex 0, so the
        // plain 24-term cyclic sum equals the k-polygon shoelace (extra terms
        // cross(v0,v0)=0; term k-1 -> pad(v0) IS the wrap term; k==0 -> all pad
        // -> cr=0). No per-term masks, no wrap select chain. ----
        unsigned wv[NS];
#pragma unroll
        for (int j = 0; j < NS; j++)
            wv[j] = s_p[(key[j] & 31u) * BS + tid];   // batched: one lgkm wait
        const unsigned w0 = wv[0];
#pragma unroll
        for (int j = 1; j < NS; j++)
            wv[j] = (j < k) ? wv[j] : w0;
        float X[NS], Y[NS];
#pragma unroll
        for (int j = 0; j < NS; j++) {
            X[j] = (float)((int)(wv[j] << 16) >> 16);   // sext low 16
            Y[j] = (float)((int)wv[j] >> 16);
        }
        float cr0 = 0.f, cr1 = 0.f, cr2 = 0.f;          // 3 rotating partials:
#pragma unroll
        for (int j = 0; j < NS; j++) {                   // breaks the add chain
            const int jn = (j + 1 < NS) ? j + 1 : 0;
            const float t = X[j] * Y[jn] - Y[j] * X[jn];
            if ((j % 3) == 0) cr0 += t; else if ((j % 3) == 1) cr1 += t; else cr2 += t;
        }
        const float cr = (cr0 + cr1) + cr2;
        // Relative coords + closed loop => translation-invariant; uniform x128
        // scale folds into the final constant (0.5 / 128^2).
        const float area = fabsf(cr) * (0.5f / 16384.f);

        // ---- IoU + loss ----
        const float a1 = pw * ph, a2 = gw * gh;
        float iou = area / (a1 + a2 - area);
        iou = fmaxf(iou, 1e-6f);
        loss = 1.f - iou + res;
    }

    // ---- block reduction: wave shuffle -> LDS -> one atomic per block ----
#pragma unroll
    for (int off = 32; off > 0; off >>= 1)
        loss += __shfl_down(loss, off, 64);
    if ((tid & 63) == 0) s_red[tid >> 6] = loss;
    __syncthreads();
    if (tid == 0) {
        float t = 0.f;
#pragma unroll
        for (int w = 0; w < BS / 64; w++) t += s_red[w];
        atomicAdd(out, t * inv_n);
    }
}

extern "C" void kernel_launch(void* const* d_in, const int* in_sizes, int n_in,
                              void* d_out, int out_size, void* d_ws, size_t ws_size,
                              hipStream_t stream)
{
    const float* pred = (const float*)d_in[0];
    const float* tgt  = (const float*)d_in[1];
    float* out = (float*)d_out;
    const int n = in_sizes[0] / 5;
    const int nblk = (n + BS - 1) / BS;

    hipMemsetAsync(out, 0, sizeof(float), stream);   // async on stream: capturable
    fpdiou_kernel<<<nblk, BS, 0, stream>>>(pred, tgt, out, n, 1.f / (float)n);
}

// Round 11
// 126.738 us; speedup vs baseline: 1.0250x; 1.0205x over previous
//
#include <hip/hip_runtime.h>

#define BS 256
#define NS 24   // candidate slots: 4 c1-corners, 4 c2-corners, 16 "intersections"

__device__ __forceinline__ float rcpf(float x) { return __builtin_amdgcn_rcpf(x); }

// Key-only compare-exchange: v_min_u32 + v_max_u32, literal indices only
// (round-4 lesson: runtime indices -> scratch).
#define CSWAPK(A, B) do {                                         \
    const unsigned ka_ = key[A], kb_ = key[B];                    \
    key[A] = ka_ < kb_ ? ka_ : kb_;                               \
    key[B] = ka_ < kb_ ? kb_ : ka_;                               \
} while (0)

// (x,y) compare-exchange by x, literal indices
#define CSW2(x, y, I, J) do {                                     \
    const bool sw_ = (x[J] < x[I]);                               \
    const float xi_ = x[I], xj_ = x[J], yi_ = y[I], yj_ = y[J];   \
    x[I] = sw_ ? xj_ : xi_;  x[J] = sw_ ? xi_ : xj_;              \
    y[I] = sw_ ? yj_ : yi_;  y[J] = sw_ ? yi_ : yj_;              \
} while (0)

__global__ __launch_bounds__(BS, 4)
void fpdiou_kernel(const float* __restrict__ pred, const float* __restrict__ tgt,
                   float* __restrict__ out, int n, float inv_n)
{
    // One u32 per slot per thread: (y_fix16 << 16) | x_fix16, coords relative to
    // pred center, scale 128. [slot][tid] layout, stride BS*4 -> bank = tid%32
    // independent of slot: conflict-free, per-thread private, no barriers.
    __shared__ unsigned s_p[NS * BS];
    __shared__ float s_red[BS / 64];

    const int tid = threadIdx.x;
    const int i = blockIdx.x * BS + tid;
    float loss = 0.f;

    if (i < n) {
        const float* pp = pred + (size_t)i * 5;
        const float* gg = tgt  + (size_t)i * 5;
        const float p0 = pp[0], p1 = pp[1], pw = pp[2], ph = pp[3], pa = pp[4];
        const float g0 = gg[0], g1 = gg[1], gw = gg[2], gh = gg[3], ga = gg[4];

        const float s1 = __sinf(pa), co1 = __cosf(pa);
        const float s2 = __sinf(ga), co2 = __cosf(ga);

        const float DX[4] = {0.5f, -0.5f, -0.5f, 0.5f};
        const float DY[4] = {0.5f,  0.5f, -0.5f, -0.5f};
        float c1x[4], c1y[4], c2x[4], c2y[4];
#pragma unroll
        for (int q = 0; q < 4; q++) {
            float dx = DX[q] * pw, dy = DY[q] * ph;
            c1x[q] = dx * co1 - dy * s1 + p0;
            c1y[q] = dx * s1 + dy * co1 + p1;
            dx = DX[q] * gw; dy = DY[q] * gh;
            c2x[q] = dx * co2 - dy * s2 + g0;
            c2y[q] = dx * s2 + dy * co2 + g1;
        }

        const float SCL = 128.f;

        // ---- FPDIoU distance term: 5-comparator sort-by-x networks ----
        float res;
        {
            float px_[4] = {c1x[0], c1x[1], c1x[2], c1x[3]};
            float py_[4] = {c1y[0], c1y[1], c1y[2], c1y[3]};
            float gx_[4] = {c2x[0], c2x[1], c2x[2], c2x[3]};
            float gy_[4] = {c2y[0], c2y[1], c2y[2], c2y[3]};
            CSW2(px_, py_, 0, 1); CSW2(px_, py_, 2, 3);
            CSW2(px_, py_, 0, 2); CSW2(px_, py_, 1, 3); CSW2(px_, py_, 1, 2);
            CSW2(gx_, gy_, 0, 1); CSW2(gx_, gy_, 2, 3);
            CSW2(gx_, gy_, 0, 2); CSW2(gx_, gy_, 1, 3); CSW2(gx_, gy_, 1, 2);
            const float d0 = gx_[0] - px_[0];
            float d = 2.f * d0 * d0;
#pragma unroll
            for (int q = 1; q < 4; q++) {
                const float dxq = px_[q] - gx_[q];
                const float dyq = py_[q] - gy_[q];
                d += dxq * dxq + dyq * dyq;
            }
            res = d * (1.f / 4194304.f);
        }

        // ---- fill 24 slots; pack coords -> LDS; validity bitmask ----
        unsigned vm = 0;
        float sx = 0.f, sy = 0.f;
        int k = 0;
        const float e = 1e-6f;

        // slots 0..3: c1 corners inside box2 (division-free threshold form)
        {
            const float ax = c2x[0], ay = c2y[0];
            const float abx = c2x[1] - ax, aby = c2y[1] - ay;
            const float adx = c2x[3] - ax, ady = c2y[3] - ay;
            const float dab = abx * abx + aby * aby;
            const float dad = adx * adx + ady * ady;
            const float lo_ab = -e * dab, hi_ab = (1.f + e) * dab;
            const float lo_ad = -e * dad, hi_ad = (1.f + e) * dad;
#pragma unroll
            for (int q = 0; q < 4; q++) {
                const float amx = c1x[q] - ax, amy = c1y[q] - ay;
                const float dot_ab = abx * amx + aby * amy;
                const float dot_ad = adx * amx + ady * amy;
                const bool m = (dot_ab > lo_ab) & (dot_ab < hi_ab)
                             & (dot_ad > lo_ad) & (dot_ad < hi_ad);
                const int xi = (int)rintf((c1x[q] - p0) * SCL);
                const int yi = (int)rintf((c1y[q] - p1) * SCL);
                s_p[q * BS + tid] = ((unsigned)yi << 16) | ((unsigned)xi & 0xFFFFu);
                if (m) { vm |= 1u << q; sx += c1x[q]; sy += c1y[q]; k++; }
            }
        }
        // slots 4..7: c2 corners inside box1
        {
            const float ax = c1x[0], ay = c1y[0];
            const float abx = c1x[1] - ax, aby = c1y[1] - ay;
            const float adx = c1x[3] - ax, ady = c1y[3] - ay;
            const float dab = abx * abx + aby * aby;
            const float dad = adx * adx + ady * ady;
            const float lo_ab = -e * dab, hi_ab = (1.f + e) * dab;
            const float lo_ad = -e * dad, hi_ad = (1.f + e) * dad;
#pragma unroll
            for (int q = 0; q < 4; q++) {
                const float amx = c2x[q] - ax, amy = c2y[q] - ay;
                const float dot_ab = abx * amx + aby * amy;
                const float dot_ad = adx * amx + ady * amy;
                const bool m = (dot_ab > lo_ab) & (dot_ab < hi_ab)
                             & (dot_ad > lo_ad) & (dot_ad < hi_ad);
                const int xi = (int)rintf((c2x[q] - p0) * SCL);
                const int yi = (int)rintf((c2y[q] - p1) * SCL);
                s_p[(4 + q) * BS + tid] = ((unsigned)yi << 16) | ((unsigned)xi & 0xFFFFu);
                if (m) { vm |= 1u << (4 + q); sx += c2x[q]; sy += c2y[q]; k++; }
            }
        }
        // slots 8..23: reference's quirky "intersections"; coords kept in VGPRs
        // for the key phase (static indexing). Wide independent math on the 16
        // corner-difference pairs (this ILP width is the r8 champion's engine).
        float iix[16], iiy[16];
#pragma unroll
        for (int a = 0; a < 4; a++) {
            const float x1 = c1x[a], y1 = c1y[a];
            const float ex = c1x[(a + 1) & 3] - x1, ey = c1y[(a + 1) & 3] - y1;
#pragma unroll
            for (int b = 0; b < 4; b++) {
                const float x3 = c2x[b], y3 = c2y[b];
                const float fx = c2x[(b + 1) & 3] - x3, fy = c2y[(b + 1) & 3] - y3;
                const float num = fy * ex - fx * ey;
                const float dx13 = x1 - x3, dy13 = y1 - y3;
                const float den_t = fx * dy13 - fy * dx13;
                const float den_u = ex * dy13 - ey * dx13;
                // t=den_t/num in (0,1) <=> den_t*num>0 && |den_t|<|num|;
                // u=-den_u/num in (0,1) <=> den_u*num<0 && |den_u|<|num|;
                // num==0 -> products +-0 -> strict cmps false (ref's t=-1 case).
                const bool m = (den_t * num > 0.f) & (fabsf(den_t) < fabsf(num))
                             & (den_u * num < 0.f) & (fabsf(den_u) < fabsf(num));
                const float t2 = den_t * rcpf(num + 1e-8f);   // reference quirk
                const float ix = fmaf(t2, ex, x1), iy = fmaf(t2, ey, y1);
                const int s = 8 + a * 4 + b;
                iix[a * 4 + b] = ix; iiy[a * 4 + b] = iy;
                const int xi = (int)rintf((ix - p0) * SCL);
                const int yi = (int)rintf((iy - p1) * SCL);
                s_p[s * BS + tid] = ((unsigned)yi << 16) | ((unsigned)xi & 0xFFFFu);
                if (m) { vm |= 1u << s; sx += ix; sy += iy; k++; }
            }
        }

        // ---- keys from REGISTERS: quantized monotone-u32(pseudo-angle) | idx ----
        const float kf = (float)(k > 0 ? k : 1);
        const float mx = sx / kf, my = sy / kf;
        unsigned key[NS];
#pragma unroll
        for (int s = 0; s < NS; s++) {
            const float vx = (s < 4) ? c1x[s] : (s < 8) ? c2x[s - 4] : iix[s - 8];
            const float vy = (s < 4) ? c1y[s] : (s < 8) ? c2y[s - 4] : iiy[s - 8];
            const float dx = vx - mx, dy = vy - my;
            const float sa = fabsf(dx) + fabsf(dy);
            float ang = copysignf(1.f - dx * rcpf(sa), dy);  // order == atan2 order
            ang = (sa == 0.f) ? 0.f : ang;
            ang = ((vm >> s) & 1u) ? ang : 1e9f;             // invalid -> back
            unsigned bb = __float_as_uint(ang);
            bb ^= (unsigned)((int)bb >> 31) | 0x80000000u;   // monotone map
            key[s] = (bb & 0xFFFFFFE0u) | (unsigned)s;       // idx = stable tiebreak
        }

        // ---- Batcher merge-exchange network, n=24 (127 comparators), keys only ----
        // p=16
        CSWAPK(0,16); CSWAPK(1,17); CSWAPK(2,18); CSWAPK(3,19);
        CSWAPK(4,20); CSWAPK(5,21); CSWAPK(6,22); CSWAPK(7,23);
        // p=8
        CSWAPK(0,8);  CSWAPK(1,9);  CSWAPK(2,10); CSWAPK(3,11);
        CSWAPK(4,12); CSWAPK(5,13); CSWAPK(6,14); CSWAPK(7,15);
        CSWAPK(8,16); CSWAPK(9,17); CSWAPK(10,18); CSWAPK(11,19);
        CSWAPK(12,20); CSWAPK(13,21); CSWAPK(14,22); CSWAPK(15,23);
        // p=4
        CSWAPK(0,4);  CSWAPK(1,5);  CSWAPK(2,6);  CSWAPK(3,7);
        CSWAPK(8,12); CSWAPK(9,13); CSWAPK(10,14); CSWAPK(11,15);
        CSWAPK(16,20); CSWAPK(17,21); CSWAPK(18,22); CSWAPK(19,23);
        CSWAPK(4,16); CSWAPK(5,17); CSWAPK(6,18); CSWAPK(7,19);
        CSWAPK(4,8);  CSWAPK(5,9);  CSWAPK(6,10); CSWAPK(7,11);
        CSWAPK(12,16); CSWAPK(13,17); CSWAPK(14,18); CSWAPK(15,19);
        // p=2
        CSWAPK(0,2);  CSWAPK(1,3);  CSWAPK(4,6);  CSWAPK(5,7);
        CSWAPK(8,10); CSWAPK(9,11); CSWAPK(12,14); CSWAPK(13,15);
        CSWAPK(16,18); CSWAPK(17,19); CSWAPK(20,22); CSWAPK(21,23);
        CSWAPK(2,16); CSWAPK(3,17); CSWAPK(6,20); CSWAPK(7,21);
        CSWAPK(2,8);  CSWAPK(3,9);  CSWAPK(6,12); CSWAPK(7,13);
        CSWAPK(10,16); CSWAPK(11,17); CSWAPK(14,20); CSWAPK(15,21);
        CSWAPK(2,4);  CSWAPK(3,5);  CSWAPK(6,8);  CSWAPK(7,9);
        CSWAPK(10,12); CSWAPK(11,13); CSWAPK(14,16); CSWAPK(15,17);
        CSWAPK(18,20); CSWAPK(19,21);
        // p=1
        CSWAPK(0,1);  CSWAPK(2,3);  CSWAPK(4,5);  CSWAPK(6,7);
        CSWAPK(8,9);  CSWAPK(10,11); CSWAPK(12,13); CSWAPK(14,15);
        CSWAPK(16,17); CSWAPK(18,19); CSWAPK(20,21); CSWAPK(22,23);
        CSWAPK(1,16); CSWAPK(3,18); CSWAPK(5,20); CSWAPK(7,22);
        CSWAPK(1,8);  CSWAPK(3,10); CSWAPK(5,12); CSWAPK(7,14);
        CSWAPK(9,16); CSWAPK(11,18); CSWAPK(13,20); CSWAPK(15,22);
        CSWAPK(1,4);  CSWAPK(3,6);  CSWAPK(5,8);  CSWAPK(7,10);
        CSWAPK(9,12); CSWAPK(11,14); CSWAPK(13,16); CSWAPK(15,18);
        CSWAPK(17,20); CSWAPK(19,22);
        CSWAPK(1,2);  CSWAPK(3,4);  CSWAPK(5,6);  CSWAPK(7,8);
        CSWAPK(9,10); CSWAPK(11,12); CSWAPK(13,14); CSWAPK(15,16);
        CSWAPK(17,18); CSWAPK(19,20); CSWAPK(21,22);

        // ---- shoelace, fully parallel form ----
        // Phase 1: batch all 24 LDS gathers (independent addrs -> one lgkm wait).
        unsigned wv[NS];
#pragma unroll
        for (int j = 0; j < NS; j++)
            wv[j] = s_p[(key[j] & 31u) * BS + tid];
        // Phase 2: unpack to static-index register arrays.
        float X[NS], Y[NS];
#pragma unroll
        for (int j = 0; j < NS; j++) {
            X[j] = (float)((int)(wv[j] << 16) >> 16);   // sext low 16
            Y[j] = (float)((int)wv[j] >> 16);
        }
        // Phase 3: independent pair terms into 3 rotating partials (breaks the
        // float-add dependency chain; no carried lx/ly state).
        float cr0 = 0.f, cr1 = 0.f, cr2 = 0.f;
#pragma unroll
        for (int j = 0; j + 1 < NS; j++) {
            const float t = (j + 1 < k) ? (X[j] * Y[j + 1] - Y[j] * X[j + 1]) : 0.f;
            if ((j % 3) == 0) cr0 += t; else if ((j % 3) == 1) cr1 += t; else cr2 += t;
        }
        // Wrap term: (X[k-1],Y[k-1]) via cndmask chain (cheap, full-rate ops).
        float xk = 0.f, yk = 0.f;
#pragma unroll
        for (int j = 0; j < NS; j++) {
            const bool w = (j == k - 1);
            xk = w ? X[j] : xk;
            yk = w ? Y[j] : yk;
        }
        const float cr = (cr0 + cr1) + (cr2 + (xk * Y[0] - yk * X[0]));
        // Relative coords + closed loop => translation-invariant; uniform x128
        // scale folds into the final constant (0.5 / 128^2).
        const float area = (k > 0) ? fabsf(cr) * (0.5f / 16384.f) : 0.f;

        // ---- IoU + loss ----
        const float a1 = pw * ph, a2 = gw * gh;
        float iou = area / (a1 + a2 - area);
        iou = fmaxf(iou, 1e-6f);
        loss = 1.f - iou + res;
    }

    // ---- block reduction: wave shuffle -> LDS -> one atomic per block ----
#pragma unroll
    for (int off = 32; off > 0; off >>= 1)
        loss += __shfl_down(loss, off, 64);
    if ((tid & 63) == 0) s_red[tid >> 6] = loss;
    __syncthreads();
    if (tid == 0) {
        float t = 0.f;
#pragma unroll
        for (int w = 0; w < BS / 64; w++) t += s_red[w];
        atomicAdd(out, t * inv_n);
    }
}

extern "C" void kernel_launch(void* const* d_in, const int* in_sizes, int n_in,
                              void* d_out, int out_size, void* d_ws, size_t ws_size,
                              hipStream_t stream)
{
    const float* pred = (const float*)d_in[0];
    const float* tgt  = (const float*)d_in[1];
    float* out = (float*)d_out;
    const int n = in_sizes[0] / 5;
    const int nblk = (n + BS - 1) / BS;

    hipMemsetAsync(out, 0, sizeof(float), stream);   // async on stream: capturable
    fpdiou_kernel<<<nblk, BS, 0, stream>>>(pred, tgt, out, n, 1.f / (float)n);
}